// Round 1
// baseline (224.871 us; speedup 1.0000x reference)
//
#include <hip/hip_runtime.h>

#define N_BONDS 50000
#define N_EDGES 600000
#define R_BONDS 4          // bonds per wave
#define WPB     4          // waves per block (256 threads)
#define BONDS_PER_BLOCK (R_BONDS * WPB)

__device__ __forceinline__ float bcast(float v, int srcLane) {
    return __builtin_bit_cast(float, __builtin_amdgcn_readlane(__builtin_bit_cast(int, v), srcLane));
}

__global__ __launch_bounds__(256, 3)
void fused_gather_segsum_mm(const float* __restrict__ bond,   // [N_BONDS][64]
                            const float* __restrict__ sph,    // [N_EDGES][64]
                            const int*   __restrict__ edges,  // [N_EDGES][2] (seg, nbr)
                            const float* __restrict__ Kmat,   // [128][64]
                            const float* __restrict__ bias,   // [64]
                            float* __restrict__ out)          // [N_BONDS][64]
{
    const int lane = threadIdx.x & 63;
    const int wid  = threadIdx.x >> 6;
    const int b0   = (blockIdx.x * WPB + wid) * R_BONDS;
    if (b0 >= N_BONDS) return;
    const int b_end = (b0 + R_BONDS < N_BONDS) ? b0 + R_BONDS : N_BONDS;

    // --- K columns for this lane (held in registers: 128 VGPR) ---
    float ktop[64], kbot[64];
    #pragma unroll
    for (int d = 0; d < 64; ++d) {
        ktop[d] = Kmat[d * 64 + lane];
        kbot[d] = Kmat[(64 + d) * 64 + lane];
    }
    const float bias_l = bias[lane];

    // --- lower_bound over sorted seg (= edges[e*2]) ---
    auto lower_bound = [&](int target) -> int {
        int lo = 0, hi = N_EDGES;
        while (lo < hi) {
            int mid = (lo + hi) >> 1;
            if (edges[mid * 2] < target) lo = mid + 1; else hi = mid;
        }
        return lo;
    };
    int e = lower_bound(b0);
    const int e_hi = lower_bound(b_end);

    // --- flush: matvec of the aggregated row (held across lanes) with K ---
    auto flush = [&](int bb, float aG, float aS) {
        float accg = 0.f, accs = 0.f;
        #pragma unroll
        for (int d = 0; d < 64; ++d) {
            accg = fmaf(bcast(aG, d), ktop[d], accg);
            accs = fmaf(bcast(aS, d), kbot[d], accs);
        }
        out[bb * 64 + lane] = accg + accs + bias_l;
    };

    int b = b0;
    float aggG = 0.f, aggS = 0.f;

    // depth-1 prefetch state
    int se = 0, nb = 0;
    float gv = 0.f, sv = 0.f;
    if (e < e_hi) {
        int2 p = ((const int2*)edges)[e];
        se = p.x; nb = p.y;
        gv = bond[nb * 64 + lane];
        sv = sph[e * 64 + lane];
    }

    while (e < e_hi) {
        const int en = e + 1;
        int se2 = 0, nb2 = 0; float gv2 = 0.f, sv2 = 0.f;
        if (en < e_hi) {
            int2 p = ((const int2*)edges)[en];
            se2 = p.x; nb2 = p.y;
            gv2 = bond[nb2 * 64 + lane];
            sv2 = sph[en * 64 + lane];
        }

        if (se != b) {                      // wave-uniform branch (se uniform)
            flush(b, aggG, aggS);
            for (int bb = b + 1; bb < se; ++bb) flush(bb, 0.f, 0.f);
            b = se; aggG = 0.f; aggS = 0.f;
        }
        aggG += gv; aggS += sv;

        se = se2; nb = nb2; gv = gv2; sv = sv2;
        e = en;
    }

    flush(b, aggG, aggS);
    for (int bb = b + 1; bb < b_end; ++bb) flush(bb, 0.f, 0.f);
}

extern "C" void kernel_launch(void* const* d_in, const int* in_sizes, int n_in,
                              void* d_out, int out_size, void* d_ws, size_t ws_size,
                              hipStream_t stream) {
    const float* bond  = (const float*)d_in[0];
    const float* sph   = (const float*)d_in[1];
    const int*   edges = (const int*)d_in[2];
    const float* Kmat  = (const float*)d_in[3];
    const float* bias  = (const float*)d_in[4];
    float* out = (float*)d_out;

    const int nblocks = (N_BONDS + BONDS_PER_BLOCK - 1) / BONDS_PER_BLOCK;
    fused_gather_segsum_mm<<<nblocks, 256, 0, stream>>>(bond, sph, edges, Kmat, bias, out);
}

// Round 2
// 102.345 us; speedup vs baseline: 2.1972x; 2.1972x over previous
//
#include <hip/hip_runtime.h>

#define N_BONDS 50000
#define N_EDGES 600000
#define R_BONDS 8          // bonds per wave (register slots)
#define WPB     4          // waves per block (256 threads)
#define BONDS_PER_BLOCK (R_BONDS * WPB)   // 32
#define CHUNK   8          // edges with loads in flight per inner step

__device__ __forceinline__ float bcastf(float v, int srcLane) {
    return __builtin_bit_cast(float, __builtin_amdgcn_readlane(__builtin_bit_cast(int, v), srcLane));
}
__device__ __forceinline__ int bcasti(int v, int srcLane) {
    return __builtin_amdgcn_readlane(v, srcLane);
}

__global__ __launch_bounds__(256, 4)
void fused_gather_segsum_mm(const float* __restrict__ bond,   // [N_BONDS][64]
                            const float* __restrict__ sph,    // [N_EDGES][64]
                            const int*   __restrict__ edges,  // [N_EDGES][2] (seg, nbr)
                            const float* __restrict__ Kmat,   // [128][64]
                            const float* __restrict__ bias,   // [64]
                            float* __restrict__ out)          // [N_BONDS][64]
{
    __shared__ float lds_K[128 * 64];   // 32 KB
    const int tid  = threadIdx.x;
    const int lane = tid & 63;
    const int wid  = tid >> 6;

    // ---- stage K into LDS (float4, coalesced), single barrier ----
    {
        const float4* src = (const float4*)Kmat;
        float4*       dst = (float4*)lds_K;
        #pragma unroll
        for (int i = 0; i < 8; ++i)
            dst[tid + i * 256] = src[tid + i * 256];
    }
    __syncthreads();

    const int b0 = blockIdx.x * BONDS_PER_BLOCK + wid * R_BONDS;
    if (b0 >= N_BONDS) return;                 // after the only barrier: safe
    int b_end = b0 + R_BONDS;
    if (b_end > N_BONDS) b_end = N_BONDS;

    // ---- per-bond register slots (aggregated features, lane = feature) ----
    float slotG[R_BONDS], slotS[R_BONDS];
    #pragma unroll
    for (int r = 0; r < R_BONDS; ++r) { slotG[r] = 0.f; slotS[r] = 0.f; }

    // ---- edge range via binary search over sorted seg ----
    auto lower_bound = [&](int target) -> int {
        int lo = 0, hi = N_EDGES;
        while (lo < hi) {
            int mid = (lo + hi) >> 1;
            if (edges[mid * 2] < target) lo = mid + 1; else hi = mid;
        }
        return lo;
    };
    int e          = lower_bound(b0);
    const int e_hi = lower_bound(b_end);

    int   b    = b0;
    float aggG = 0.f, aggS = 0.f;
    const int2* edges2 = (const int2*)edges;

    while (e < e_hi) {
        int wlen = e_hi - e;
        if (wlen > 64) wlen = 64;
        int2 p = make_int2(-1, 0);
        if (lane < wlen) p = edges2[e + lane];   // one coalesced index load / 64 edges

        for (int c = 0; c < wlen; c += CHUNK) {
            int m = wlen - c;
            if (m > CHUNK) m = CHUNK;

            // issue all loads for this chunk (16 in flight)
            float gv[CHUNK], sv[CHUNK];
            int   seA[CHUNK];
            #pragma unroll
            for (int j = 0; j < CHUNK; ++j) {
                seA[j]  = bcasti(p.x, c + j);
                int nbj = bcasti(p.y, c + j);
                if (j < m) {
                    gv[j] = bond[nbj * 64 + lane];
                    sv[j] = __builtin_nontemporal_load(&sph[(e + c + j) * 64 + lane]);
                } else { gv[j] = 0.f; sv[j] = 0.f; }
            }

            // accumulate (wave-uniform segment logic)
            #pragma unroll
            for (int j = 0; j < CHUNK; ++j) {
                if (j < m) {
                    int se = seA[j];
                    if (se != b) {               // close current bond into its slot
                        #pragma unroll
                        for (int r = 0; r < R_BONDS; ++r)
                            if (b0 + r == b) { slotG[r] = aggG; slotS[r] = aggS; }
                        b = se; aggG = 0.f; aggS = 0.f;
                    }
                    aggG += gv[j];
                    aggS += sv[j];
                }
            }
        }
        e += wlen;
    }
    // final close
    #pragma unroll
    for (int r = 0; r < R_BONDS; ++r)
        if (b0 + r == b) { slotG[r] = aggG; slotS[r] = aggS; }

    // ---- deferred matmul: 8 bonds share each K element ----
    const float bias_l = bias[lane];
    float acc[R_BONDS];
    #pragma unroll
    for (int r = 0; r < R_BONDS; ++r) acc[r] = bias_l;

    #pragma unroll 4
    for (int d = 0; d < 64; ++d) {
        float kt = lds_K[d * 64 + lane];          // conflict-free: lane-consecutive
        float kb = lds_K[(64 + d) * 64 + lane];
        #pragma unroll
        for (int r = 0; r < R_BONDS; ++r) {
            acc[r] = fmaf(bcastf(slotG[r], d), kt, acc[r]);
            acc[r] = fmaf(bcastf(slotS[r], d), kb, acc[r]);
        }
    }

    #pragma unroll
    for (int r = 0; r < R_BONDS; ++r)
        if (b0 + r < N_BONDS)
            __builtin_nontemporal_store(acc[r], &out[(b0 + r) * 64 + lane]);
}

extern "C" void kernel_launch(void* const* d_in, const int* in_sizes, int n_in,
                              void* d_out, int out_size, void* d_ws, size_t ws_size,
                              hipStream_t stream) {
    const float* bond  = (const float*)d_in[0];
    const float* sph   = (const float*)d_in[1];
    const int*   edges = (const int*)d_in[2];
    const float* Kmat  = (const float*)d_in[3];
    const float* bias  = (const float*)d_in[4];
    float* out = (float*)d_out;

    const int nblocks = (N_BONDS + BONDS_PER_BLOCK - 1) / BONDS_PER_BLOCK;
    fused_gather_segsum_mm<<<nblocks, 256, 0, stream>>>(bond, sph, edges, Kmat, bias, out);
}